// Round 1
// baseline (691989.355 us; speedup 1.0000x reference)
//
#include <hip/hip_runtime.h>
#include <hip/hip_bf16.h>

// ---------------- model dims ----------------
#define V_   128
#define L_   300
#define EU_  256
#define GU_  1024    // 4*EU
#define NSTEP (299*128)   // 38272 decoder steps

typedef float v2f __attribute__((ext_vector_type(2)));

__device__ __forceinline__ v2f mk2(float x, float y) { v2f r; r.x = x; r.y = y; return r; }
__device__ __forceinline__ float sigmoidf_(float x) { return 1.f / (1.f + __expf(-x)); }
__device__ __forceinline__ float tanhf_(float x) { return 2.f / (1.f + __expf(-2.f * x)) - 1.f; }

// z[j] = dot(h[0:256], Wcol_j) with Wcol in registers (v2f pairs), h broadcast from LDS
__device__ __forceinline__ float dot256(const v2f* wreg, const float4* h4) {
    v2f a0 = mk2(0.f, 0.f), a1 = mk2(0.f, 0.f), a2 = mk2(0.f, 0.f), a3 = mk2(0.f, 0.f);
#pragma unroll
    for (int q = 0; q < 64; q += 2) {
        float4 ha = h4[q];
        a0 += mk2(ha.x, ha.y) * wreg[2 * q];
        a1 += mk2(ha.z, ha.w) * wreg[2 * q + 1];
        float4 hb = h4[q + 1];
        a2 += mk2(hb.x, hb.y) * wreg[2 * q + 2];
        a3 += mk2(hb.z, hb.w) * wreg[2 * q + 3];
    }
    v2f s = (a0 + a1) + (a2 + a3);
    return s.x + s.y;
}

// ---------------- tok extraction ----------------
__global__ void tok_kernel(const float* __restrict__ din, int* __restrict__ tok) {
    int l = blockIdx.x * 64 + threadIdx.x;
    if (l >= 299) return;
    int t = 0;
    for (int v = 0; v < 128; ++v)
        if (din[l * 128 + v] > 0.5f) t = v;
    tok[l] = t;
}

// ---------------- STFT conv1 (3x3x1->256) + relu + 2x2 maxpool ----------------
// in [64,513], out [31,255,256]
__global__ void stft_conv1_kernel(const float* __restrict__ in, const float* __restrict__ w,
                                  const float* __restrict__ b, float* __restrict__ out) {
    int c = threadIdx.x;
    int blk = blockIdx.x;
    int pw = blk % 255, ph = blk / 255;
    int h0 = 2 * ph, w0 = 2 * pw;
    float pin[4][4];
#pragma unroll
    for (int r = 0; r < 4; ++r)
#pragma unroll
        for (int s = 0; s < 4; ++s) pin[r][s] = in[(h0 + r) * 513 + (w0 + s)];
    float acc[2][2] = {};
#pragma unroll
    for (int dh = 0; dh < 3; ++dh)
#pragma unroll
        for (int dw = 0; dw < 3; ++dw) {
            float wv = w[(dh * 3 + dw) * 256 + c];
            acc[0][0] += pin[dh][dw] * wv;
            acc[0][1] += pin[dh][dw + 1] * wv;
            acc[1][0] += pin[dh + 1][dw] * wv;
            acc[1][1] += pin[dh + 1][dw + 1] * wv;
        }
    float m = fmaxf(fmaxf(acc[0][0], acc[0][1]), fmaxf(acc[1][0], acc[1][1]));
    out[(ph * 255 + pw) * 256 + c] = fmaxf(m + b[c], 0.f);
}

// ---------------- STFT conv2 (3x3x256->256) + relu + 2x2 maxpool ----------------
// in [31,255,256], out [14,126,256]; block = (ph, group of 3 pw), 256 threads = out channel
__global__ void stft_conv2_kernel(const float* __restrict__ P1, const float* __restrict__ w,
                                  const float* __restrict__ b, float* __restrict__ out) {
    __shared__ float patch[4 * 8 * 256];  // [r][cc][ci]
    int c = threadIdx.x;
    int blk = blockIdx.x;
    int pwg = blk % 42, ph = blk / 42;
    int pw0 = pwg * 3;
    int r0 = 2 * ph, c0 = 2 * pw0;
    for (int i = c; i < 4 * 8 * 256; i += 256) {
        int ci = i & 255;
        int t = i >> 8;
        int cc = t & 7, r = t >> 3;
        patch[i] = P1[((r0 + r) * 255 + (c0 + cc)) * 256 + ci];
    }
    __syncthreads();
    float acc[3][2][2] = {};
    for (int dh = 0; dh < 3; ++dh) {
        for (int ci = 0; ci < 256; ++ci) {
            float p0[8], p1[8];
#pragma unroll
            for (int x = 0; x < 8; ++x) {
                p0[x] = patch[(dh * 8 + x) * 256 + ci];
                p1[x] = patch[((dh + 1) * 8 + x) * 256 + ci];
            }
#pragma unroll
            for (int dw = 0; dw < 3; ++dw) {
                float wv = w[((dh * 3 + dw) * 256 + ci) * 256 + c];
#pragma unroll
                for (int o = 0; o < 3; ++o)
#pragma unroll
                    for (int s = 0; s < 2; ++s) {
                        acc[o][0][s] += p0[2 * o + s + dw] * wv;
                        acc[o][1][s] += p1[2 * o + s + dw] * wv;
                    }
            }
        }
    }
    float bv = b[c];
#pragma unroll
    for (int o = 0; o < 3; ++o) {
        float m = fmaxf(fmaxf(acc[o][0][0], acc[o][0][1]), fmaxf(acc[o][1][0], acc[o][1][1]));
        out[(ph * 126 + (pw0 + o)) * 256 + c] = fmaxf(m + bv, 0.f);
    }
}

// ---------------- STFT input projection: X[14,32256] @ Wi[32256,1024], split-K ----------------
__global__ void xprojS_partial_kernel(const float* __restrict__ X, const float* __restrict__ Wi,
                                      float* __restrict__ part) {
    __shared__ float xbuf[14 * 504];
    int tid = threadIdx.x;
    int kc = blockIdx.x & 63;
    int cb = blockIdx.x >> 6;
    int col = cb * 256 + tid;
    int k0 = kc * 504;
    for (int i = tid; i < 14 * 504; i += 256) {
        int t = i / 504;
        int kk = i - t * 504;
        xbuf[i] = X[t * 32256 + k0 + kk];
    }
    __syncthreads();
    float acc[14] = {};
    for (int kk = 0; kk < 504; ++kk) {
        float wv = Wi[(size_t)(k0 + kk) * 1024 + col];
#pragma unroll
        for (int t = 0; t < 14; ++t) acc[t] += xbuf[t * 504 + kk] * wv;
    }
#pragma unroll
    for (int t = 0; t < 14; ++t) part[(kc * 14 + t) * 1024 + col] = acc[t];
}

__global__ void xprojS_reduce_kernel(const float* __restrict__ part, const float* __restrict__ bias,
                                     float* __restrict__ xp) {
    int idx = blockIdx.x * 256 + threadIdx.x;  // < 14*1024
    int t = idx >> 10, col = idx & 1023;
    float s = bias[col];
    for (int kc = 0; kc < 64; ++kc) s += part[(kc * 14 + t) * 1024 + col];
    xp[idx] = s;
}

// ---------------- wave conv1 (k=3, 1024->256) + relu + pool2 ----------------
// in [256,1024], out [127,256]
__global__ void wave_conv1_kernel(const float* __restrict__ in, const float* __restrict__ w,
                                  const float* __restrict__ b, float* __restrict__ out) {
    __shared__ float patch[4 * 1024];
    int c = threadIdx.x, t = blockIdx.x;
    for (int i = c; i < 4 * 1024; i += 256) patch[i] = in[(2 * t) * 1024 + i];
    __syncthreads();
    float acc0 = 0.f, acc1 = 0.f;
    for (int dt = 0; dt < 3; ++dt)
        for (int ci = 0; ci < 1024; ++ci) {
            float wv = w[(dt * 1024 + ci) * 256 + c];
            acc0 += patch[dt * 1024 + ci] * wv;
            acc1 += patch[(dt + 1) * 1024 + ci] * wv;
        }
    out[t * 256 + c] = fmaxf(fmaxf(acc0, acc1) + b[c], 0.f);
}

// ---------------- wave conv2 (k=3, 256->256) + relu + pool2 ----------------
// in [127,256], out [62,256]
__global__ void wave_conv2_kernel(const float* __restrict__ in, const float* __restrict__ w,
                                  const float* __restrict__ b, float* __restrict__ out) {
    __shared__ float patch[4 * 256];
    int c = threadIdx.x, t = blockIdx.x;
    for (int i = c; i < 4 * 256; i += 256) patch[i] = in[(2 * t) * 256 + i];
    __syncthreads();
    float acc0 = 0.f, acc1 = 0.f;
    for (int dt = 0; dt < 3; ++dt)
        for (int ci = 0; ci < 256; ++ci) {
            float wv = w[(dt * 256 + ci) * 256 + c];
            acc0 += patch[dt * 256 + ci] * wv;
            acc1 += patch[(dt + 1) * 256 + ci] * wv;
        }
    out[t * 256 + c] = fmaxf(fmaxf(acc0, acc1) + b[c], 0.f);
}

// ---------------- wave input projection X[62,256] @ Wi[256,1024] + b ----------------
__global__ void xprojW_kernel(const float* __restrict__ X, const float* __restrict__ Wi,
                              const float* __restrict__ bias, float* __restrict__ xp) {
    int idx = blockIdx.x * 256 + threadIdx.x;  // 62*1024
    int t = idx >> 10, col = idx & 1023;
    float s = bias[col];
    for (int k = 0; k < 256; ++k) s += X[t * 256 + k] * Wi[k * 1024 + col];
    xp[idx] = s;
}

// ---------------- encoder LSTM (xproj precomputed, bias folded in), h0=c0=0 ----------------
__global__ __launch_bounds__(1024) void lstm_enc_kernel(const float* __restrict__ xp,
                                                        const float* __restrict__ Wh, int T,
                                                        float* __restrict__ h_out,
                                                        float* __restrict__ c_out) {
    __shared__ __align__(16) float hbuf[256];
    __shared__ float zbuf[1024];
    int j = threadIdx.x;
    v2f wreg[128];
#pragma unroll
    for (int kk = 0; kk < 128; ++kk)
        wreg[kk] = mk2(Wh[(2 * kk) * 1024 + j], Wh[(2 * kk + 1) * 1024 + j]);
    float c = 0.f;
    if (j < 256) hbuf[j] = 0.f;
    __syncthreads();
    for (int t = 0; t < T; ++t) {
        float z = xp[t * 1024 + j] + dot256(wreg, (const float4*)hbuf);
        zbuf[j] = z;
        __syncthreads();
        if (j < 256) {
            float zi = zbuf[j], zf = zbuf[j + 256], zg = zbuf[j + 512], zo = zbuf[j + 768];
            c = sigmoidf_(zf) * c + sigmoidf_(zi) * tanhf_(zg);
            hbuf[j] = sigmoidf_(zo) * tanhf_(c);
        }
        __syncthreads();
    }
    if (j < 256) {
        h_out[j] = hbuf[j];
        c_out[j] = c;
    }
}

// ---------------- state reducers: [sh|wh]@rh_w+rh_b, [sc|wc]@rc_w+rc_b ----------------
__global__ void reduce_state_kernel(const float* __restrict__ sh, const float* __restrict__ sc,
                                    const float* __restrict__ wh, const float* __restrict__ wc,
                                    const float* __restrict__ rhw, const float* __restrict__ rhb,
                                    const float* __restrict__ rcw, const float* __restrict__ rcb,
                                    float* __restrict__ h0, float* __restrict__ c0) {
    int m = threadIdx.x;  // 256
    float ah = rhb[m], ac = rcb[m];
    for (int k = 0; k < 256; ++k) {
        ah += sh[k] * rhw[k * 256 + m];
        ac += sc[k] * rcw[k * 256 + m];
    }
    for (int k = 0; k < 256; ++k) {
        ah += wh[k] * rhw[(256 + k) * 256 + m];
        ac += wc[k] * rcw[(256 + k) * 256 + m];
    }
    h0[m] = ah;
    c0[m] = ac;
}

// ---------------- a0/a1 = emb[s] @ d_Wi + d_b ----------------
__global__ void a01_kernel(const float* __restrict__ emb, const float* __restrict__ Wi,
                           const float* __restrict__ bias, float* __restrict__ a01) {
    int idx = blockIdx.x * 256 + threadIdx.x;  // 2048
    int s = idx >> 10, j = idx & 1023;
    float acc = bias[j];
    for (int k = 0; k < 256; ++k) acc += emb[s * 256 + k] * Wi[k * 1024 + j];
    a01[idx] = acc;
}

// ---------------- decoder chain: 38272 sequential LSTM steps, h history -> bf16 ----------------
__global__ __launch_bounds__(1024) void lstm_dec_kernel(
    const float* __restrict__ Wh, const float* __restrict__ a0, const float* __restrict__ a1,
    const int* __restrict__ tok, const float* __restrict__ h0, const float* __restrict__ c0,
    __hip_bfloat16* __restrict__ h_hist) {
    __shared__ __align__(16) float hbuf[256];
    __shared__ float zbuf[1024];
    int j = threadIdx.x;
    v2f wreg[128];
#pragma unroll
    for (int kk = 0; kk < 128; ++kk)
        wreg[kk] = mk2(Wh[(2 * kk) * 1024 + j], Wh[(2 * kk + 1) * 1024 + j]);
    float a0r = a0[j], a1r = a1[j];
    float c = 0.f;
    if (j < 256) {
        hbuf[j] = h0[j];
        c = c0[j];
    }
    __syncthreads();
    int step = 0;
#pragma unroll 1
    for (int l = 0; l < 299; ++l) {
        int tk = tok[l];
#pragma unroll 1
        for (int v = 0; v < 128; ++v) {
            float a = (v == tk) ? a1r : a0r;
            float z = a + dot256(wreg, (const float4*)hbuf);
            zbuf[j] = z;
            __syncthreads();
            if (j < 256) {
                float zi = zbuf[j], zf = zbuf[j + 256], zg = zbuf[j + 512], zo = zbuf[j + 768];
                c = sigmoidf_(zf) * c + sigmoidf_(zi) * tanhf_(zg);
                float h = sigmoidf_(zo) * tanhf_(c);
                hbuf[j] = h;
                h_hist[(size_t)step * 256 + j] = __float2bfloat16(h);
            }
            __syncthreads();
            ++step;
        }
    }
}

// ---------------- projection + softmax epilogue: 4 rows/block, 256 threads ----------------
__global__ __launch_bounds__(256) void proj_softmax_kernel(const __hip_bfloat16* __restrict__ hh,
                                                           const float* __restrict__ Wo,
                                                           const float* __restrict__ bo,
                                                           float* __restrict__ out) {
    __shared__ float hrows[4][256];
    __shared__ float llds[4][128];
    int tid = threadIdx.x;
    int rbase = blockIdx.x * 4;
    for (int i = tid; i < 1024; i += 256)
        hrows[i >> 8][i & 255] = __bfloat162float(hh[(size_t)rbase * 256 + i]);
    __syncthreads();
    int w = tid & 127, half = tid >> 7;
    int k0 = half * 128;
    float acc[4] = {};
    for (int k = 0; k < 128; ++k) {
        float wv = Wo[(k0 + k) * 128 + w];
#pragma unroll
        for (int r = 0; r < 4; ++r) acc[r] += hrows[r][k0 + k] * wv;
    }
    if (half == 0) {
#pragma unroll
        for (int r = 0; r < 4; ++r) llds[r][w] = acc[r] + bo[w];
    }
    __syncthreads();
    if (half == 1) {
#pragma unroll
        for (int r = 0; r < 4; ++r) llds[r][w] += acc[r];
    }
    __syncthreads();
    int rr = tid >> 6, lane = tid & 63;  // wave rr handles row rr
    float x0 = llds[rr][lane], x1 = llds[rr][lane + 64];
    float mx = fmaxf(x0, x1);
    for (int off = 32; off > 0; off >>= 1) mx = fmaxf(mx, __shfl_xor(mx, off));
    float e0 = __expf(x0 - mx), e1 = __expf(x1 - mx);
    float sm = e0 + e1;
    for (int off = 32; off > 0; off >>= 1) sm += __shfl_xor(sm, off);
    float inv = 1.f / sm;
    int row = rbase + rr;
    int l = row >> 7, v = row & 127;
    float* op = out + ((size_t)v * 300 + l) * 128;
    op[lane] = e0 * inv;
    op[lane + 64] = e1 * inv;
}

// ---------------- zero last time slot l=299 ----------------
__global__ void zero_tail_kernel(float* __restrict__ out) {
    int idx = blockIdx.x * 256 + threadIdx.x;  // 128*128
    int v = idx >> 7, w = idx & 127;
    out[((size_t)v * 300 + 299) * 128 + w] = 0.f;
}

extern "C" void kernel_launch(void* const* d_in, const int* in_sizes, int n_in, void* d_out,
                              int out_size, void* d_ws, size_t ws_size, hipStream_t stream) {
    const float* stft = (const float*)d_in[0];
    const float* wave = (const float*)d_in[1];
    const float* din = (const float*)d_in[2];
    const float* s_cw1 = (const float*)d_in[3];
    const float* s_cb1 = (const float*)d_in[4];
    const float* s_cw2 = (const float*)d_in[5];
    const float* s_cb2 = (const float*)d_in[6];
    const float* s_Wi = (const float*)d_in[7];
    const float* s_Wh = (const float*)d_in[8];
    const float* s_b = (const float*)d_in[9];
    const float* w_cw1 = (const float*)d_in[10];
    const float* w_cb1 = (const float*)d_in[11];
    const float* w_cw2 = (const float*)d_in[12];
    const float* w_cb2 = (const float*)d_in[13];
    const float* w_Wi = (const float*)d_in[14];
    const float* w_Wh = (const float*)d_in[15];
    const float* w_b = (const float*)d_in[16];
    const float* rh_w = (const float*)d_in[17];
    const float* rh_b = (const float*)d_in[18];
    const float* rc_w = (const float*)d_in[19];
    const float* rc_b = (const float*)d_in[20];
    const float* emb = (const float*)d_in[21];
    const float* d_Wi = (const float*)d_in[22];
    const float* d_Wh = (const float*)d_in[23];
    const float* d_b = (const float*)d_in[24];
    const float* out_w = (const float*)d_in[25];
    const float* out_b = (const float*)d_in[26];
    float* out = (float*)d_out;
    float* ws = (float*)d_ws;

    // workspace layout (float offsets)
    const size_t off_P1s = 0;                         // 31*255*256 = 2023680
    const size_t off_P2s = off_P1s + 2023680;         // 14*126*256 = 451584
    const size_t off_partS = off_P2s + 451584;        // 64*14*1024 = 917504
    const size_t off_P1w = off_partS + 917504;        // 127*256 = 32512
    const size_t off_P2w = off_P1w + 32512;           // 62*256 = 15872
    const size_t off_xprojS = off_P2w + 15872;        // 14*1024
    const size_t off_xprojW = off_xprojS + 14336;     // 62*1024
    const size_t off_sh = off_xprojW + 63488;         // 4*256 states
    const size_t off_sc = off_sh + 256;
    const size_t off_wh = off_sc + 256;
    const size_t off_wc = off_wh + 256;
    const size_t off_h0 = off_wc + 256;
    const size_t off_c0 = off_h0 + 256;
    const size_t off_a01 = off_c0 + 256;              // 2048
    const size_t off_tok = off_a01 + 2048;            // 299 ints (512 slots)
    const size_t off_hh = off_tok + 512;              // bf16 region: 38272*256 bf16
    __hip_bfloat16* h_hist = (__hip_bfloat16*)(ws + off_hh);
    int* tok = (int*)(ws + off_tok);

    tok_kernel<<<5, 64, 0, stream>>>(din, tok);

    // STFT branch
    stft_conv1_kernel<<<31 * 255, 256, 0, stream>>>(stft, s_cw1, s_cb1, ws + off_P1s);
    stft_conv2_kernel<<<14 * 42, 256, 0, stream>>>(ws + off_P1s, s_cw2, s_cb2, ws + off_P2s);
    xprojS_partial_kernel<<<256, 256, 0, stream>>>(ws + off_P2s, s_Wi, ws + off_partS);
    xprojS_reduce_kernel<<<56, 256, 0, stream>>>(ws + off_partS, s_b, ws + off_xprojS);
    lstm_enc_kernel<<<1, 1024, 0, stream>>>(ws + off_xprojS, s_Wh, 14, ws + off_sh, ws + off_sc);

    // waveform branch
    wave_conv1_kernel<<<127, 256, 0, stream>>>(wave, w_cw1, w_cb1, ws + off_P1w);
    wave_conv2_kernel<<<62, 256, 0, stream>>>(ws + off_P1w, w_cw2, w_cb2, ws + off_P2w);
    xprojW_kernel<<<248, 256, 0, stream>>>(ws + off_P2w, w_Wi, w_b, ws + off_xprojW);
    lstm_enc_kernel<<<1, 1024, 0, stream>>>(ws + off_xprojW, w_Wh, 62, ws + off_wh, ws + off_wc);

    // reducers + decoder precompute
    reduce_state_kernel<<<1, 256, 0, stream>>>(ws + off_sh, ws + off_sc, ws + off_wh, ws + off_wc,
                                               rh_w, rh_b, rc_w, rc_b, ws + off_h0, ws + off_c0);
    a01_kernel<<<8, 256, 0, stream>>>(emb, d_Wi, d_b, ws + off_a01);

    // sequential decoder chain (critical path)
    lstm_dec_kernel<<<1, 1024, 0, stream>>>(d_Wh, ws + off_a01, ws + off_a01 + 1024, tok,
                                            ws + off_h0, ws + off_c0, h_hist);

    // parallel epilogue
    proj_softmax_kernel<<<NSTEP / 4, 256, 0, stream>>>(h_hist, out_w, out_b, out);
    zero_tail_kernel<<<64, 256, 0, stream>>>(out);
}